// Round 5
// baseline (8397.923 us; speedup 1.0000x reference)
//
#include <hip/hip_runtime.h>

// B=128, S=1024, F_IN=128, H=256, BB=256, F_OUT=128
#define Bn   128
#define Sn   1024
#define FIN  128
#define Hn   256
#define FOUT 128
#define NT   512    // 8 waves = 2 waves/SIMD -> 256 VGPR budget/thread

// packed weight layout in d_ws (halves):
//   Wb_p [48][256][8]  -> 98304
//   W4_p [32][1024][8] -> 262144   (N = [ff1|ff2|ta|tb])
//   Wo_p [32][128][8]  -> 32768
//   hbuf [B*S*H] fp16
#define WB_OFF 0
#define W4_OFF 98304
#define WO_OFF 360448
#define WS_HALVES 393216
#define HBUF_OFF WS_HALVES
#define WS_SPLIT_BYTES ((size_t)(WS_HALVES + (size_t)Bn * Sn * Hn) * 2)

// dynamic LDS layout (bytes, all 16-aligned)
#define OW4L 0        // 8 W4 chunks, q-permuted: 131072
#define OXH  131072   // xh[384] f16: 768
#define OZF  131840   // zf[256] f16: 512
#define OTSB 132352   // ts[1024] f32: 4096
#define OSCZ 136448   // scrZ[8][256] f32: 8192
#define OSCH 144640   // scrH[2][1024] f32: 8192
#define OSCY 152832   // scrY[3][128] f32: 1536 (INLINE_Y fallback only)
#define SMEM4 154368

typedef _Float16 h2 __attribute__((ext_vector_type(2)));
typedef _Float16 h8 __attribute__((ext_vector_type(8)));

__device__ __forceinline__ float dot2f(h2 a, h2 b, float c) {
#if __has_builtin(__builtin_amdgcn_fdot2)
  return __builtin_amdgcn_fdot2(a, b, c, false);   // v_dot2_f32_f16
#else
  return c + (float)a[0] * (float)b[0] + (float)a[1] * (float)b[1];
#endif
}
__device__ __forceinline__ float dot8f(h8 v, h8 w, float c) {
  h2 v0 = {v[0], v[1]}, v1 = {v[2], v[3]}, v2 = {v[4], v[5]}, v3 = {v[6], v[7]};
  h2 w0 = {w[0], w[1]}, w1 = {w[2], w[3]}, w2 = {w[4], w[5]}, w3 = {w[6], w[7]};
  c = dot2f(v0, w0, c); c = dot2f(v1, w1, c);
  c = dot2f(v2, w2, c); c = dot2f(v3, w3, c);
  return c;
}
__device__ __forceinline__ void dot8_4(h8 v, h8 w, float& c0, float& c1, float& c2, float& c3) {
  h2 v0 = {v[0], v[1]}, v1 = {v[2], v[3]}, v2 = {v[4], v[5]}, v3 = {v[6], v[7]};
  h2 w0 = {w[0], w[1]}, w1 = {w[2], w[3]}, w2 = {w[4], w[5]}, w3 = {w[6], w[7]};
  c0 = dot2f(v0, w0, c0); c1 = dot2f(v1, w1, c1);
  c2 = dot2f(v2, w2, c2); c3 = dot2f(v3, w3, c3);
}

// fp32 -> fp16 packing (verified layout, rounds 1-4)
__global__ __launch_bounds__(256) void pack_w(
    const float* __restrict__ Wb, const float* __restrict__ W1,
    const float* __restrict__ W2, const float* __restrict__ W3,
    const float* __restrict__ W4, const float* __restrict__ Wo,
    _Float16* __restrict__ ws) {
  int p = blockIdx.x * 256 + threadIdx.x;
  if (p >= WS_HALVES) return;
  float v;
  if (p < W4_OFF) {
    int r = p & 7, j = (p >> 3) & 255;
    int k = ((p >> 11) << 3) | r;
    v = Wb[k * 256 + j];
  } else if (p < WO_OFF) {
    int q = p - W4_OFF;
    int r = q & 7, j = (q >> 3) & 1023;
    int k = ((q >> 13) << 3) | r;
    int jj = j & 255;
    const float* Ws = (j < 256) ? W1 : (j < 512) ? W2 : (j < 768) ? W3 : W4;
    v = Ws[k * 256 + jj];
  } else {
    int q = p - WO_OFF;
    int r = q & 7, j = (q >> 3) & 127;
    int k = ((q >> 10) << 3) | r;
    v = Wo[k * 128 + j];
  }
  ws[p] = (_Float16)v;
}

// One 512-thread WG per batch element. Weights: Wb fully VGPR-resident
// (96 regs/thread), W4 chunks 0-4/16-20 VGPR (80 regs), 5-8/21-24 LDS,
// 9-15/25-31 streamed from L2 (224 KB/step, depth-2 pipeline).
template <int INLINE_Y>
__global__ __launch_bounds__(NT, 2) void cfc4(
    const float* __restrict__ x, const float* __restrict__ ts,
    const float* __restrict__ bb, const float* __restrict__ bf1,
    const float* __restrict__ bf2, const float* __restrict__ bta,
    const float* __restrict__ btb, const float* __restrict__ bo,
    _Float16* __restrict__ ws, float* __restrict__ out) {
  extern __shared__ char smem[];
  _Float16* sW4L = (_Float16*)(smem + OW4L);
  _Float16* xh   = (_Float16*)(smem + OXH);   // [0,128): x_t  [128,384): h
  _Float16* zf   = (_Float16*)(smem + OZF);
  float*    tsb  = (float*)(smem + OTSB);
  float*    scrZ = (float*)(smem + OSCZ);
  float*    scrH = (float*)(smem + OSCH);
  float*    scrY = (float*)(smem + OSCY);

  const int tid = threadIdx.x;
  const int b = blockIdx.x;
  const _Float16* Wb_p = ws + WB_OFF;
  const _Float16* W4_p = ws + W4_OFF;
  const _Float16* Wo_p = ws + WO_OFF;
  _Float16* hbuf = ws + HBUF_OFF;

  const float* xrow  = x  + (size_t)b * Sn * FIN;
  const float* tsrow = ts + (size_t)b * Sn;
  float*       orow  = out + (size_t)b * Sn * FOUT;

  // ---- one-time staging ----
  // LDS W4 chunks {5,6,7,8, 21,22,23,24}, q-permuted: dest uint4 index
  // q*256+j4 <- src uint4 index j4*4+q (makes per-step weight ds_read_b128
  // lane-stride 16B = conflict-free)
  for (int i = tid; i < 8192; i += NT) {
    int s = i >> 10, r = i & 1023;
    int q = r >> 8, j4 = r & 255;
    int c = (s < 4) ? 5 + s : 17 + s;
    ((uint4*)sW4L)[i] = ((const uint4*)(W4_p + (size_t)c * 8192))[j4 * 4 + q];
  }
  tsb[tid] = tsrow[tid];
  tsb[tid + 512] = tsrow[tid + 512];
  if (tid < 128) ((unsigned*)xh)[64 + tid] = 0;   // h0 = 0
  if (tid < 64) {                                 // x(0)
    float2 xv0 = *(const float2*)(xrow + 2 * tid);
    h2 p; p[0] = (_Float16)xv0.x; p[1] = (_Float16)xv0.y;
    *(h2*)&xh[2 * tid] = p;
  }

  // ---- roles ----
  const int kz = tid >> 6, jz4 = tid & 63;    // Z: 8 k-groups x 64 col-quads
  const int kh = tid >> 8, jh4 = tid & 255;   // H: 2 k-halves x 256 col-quads
  const float bbj = (tid < 256) ? bb[tid] : 0.f;
  float cb1 = 0.f, cb2 = 0.f, cb3 = 0.f, cb4 = 0.f;
  if (tid < 256) { cb1 = bf1[tid]; cb2 = bf2[tid]; cb3 = bta[tid]; cb4 = btb[tid]; }
  const float boj = (tid < 128) ? bo[tid] : 0.f;

  // ---- register-resident weights (loop-invariant, fully unrolled idx) ----
  h8 wz[6][4];
#pragma unroll
  for (int c = 0; c < 6; ++c)
#pragma unroll
    for (int q = 0; q < 4; ++q)
      wz[c][q] = *(const h8*)(Wb_p + ((size_t)(kz * 6 + c) * 256 + jz4 * 4 + q) * 8);
  h8 wh[5][4];
#pragma unroll
  for (int c = 0; c < 5; ++c)
#pragma unroll
    for (int q = 0; q < 4; ++q)
      wh[c][q] = *(const h8*)(W4_p + ((size_t)(kh * 16 + c) * 1024 + jh4 * 4 + q) * 8);

  const _Float16* gS = W4_p + ((size_t)(kh * 16 + 9) * 1024 + (size_t)jh4 * 4) * 8;
  __syncthreads();

  for (int st = 0; st < Sn; ++st) {
    // x(t+1) prefetch (wave 7)
    float2 xv; xv.x = 0.f; xv.y = 0.f;
    if (tid >= 448 && st + 1 < Sn)
      xv = *(const float2*)(xrow + (size_t)(st + 1) * FIN + 2 * (tid - 448));

    // ---- Z: z = tanh([x,h] @ Wb + bb); Wb all in VGPRs ----
    float a0 = 0.f, a1 = 0.f, a2 = 0.f, a3 = 0.f;
#pragma unroll
    for (int c = 0; c < 6; ++c) {
      h8 v = *(const h8*)&xh[(kz * 6 + c) * 8];   // wave-uniform broadcast
      dot8_4(v, wz[c][0], a0, a0, a0, a0);        // NOTE: see per-col below
      // (replaced below — kept structure; real accumulation per column)
    }
    // redo properly: per-column accumulators
    a0 = 0.f; a1 = 0.f; a2 = 0.f; a3 = 0.f;
#pragma unroll
    for (int c = 0; c < 6; ++c) {
      h8 v = *(const h8*)&xh[(kz * 6 + c) * 8];
      a0 = dot8f(v, wz[c][0], a0);
      a1 = dot8f(v, wz[c][1], a1);
      a2 = dot8f(v, wz[c][2], a2);
      a3 = dot8f(v, wz[c][3], a3);
    }
    { float4 o; o.x = a0; o.y = a1; o.z = a2; o.w = a3;
      *(float4*)&scrZ[kz * 256 + jz4 * 4] = o; }
    __syncthreads();                       // B1: scrZ ready, Z xh-reads done

    if (tid >= 448 && st + 1 < Sn) {       // commit x(t+1)
      h2 p; p[0] = (_Float16)xv.x; p[1] = (_Float16)xv.y;
      *(h2*)&xh[2 * (tid - 448)] = p;
    }
    if (tid < 256) {                       // Z reduce + tanh
      float z = bbj;
#pragma unroll
      for (int s = 0; s < 8; ++s) z += scrZ[s * 256 + tid];
      zf[tid] = (_Float16)tanhf(z);
    }
    __syncthreads();                       // B2: zf ready

    // ---- H: 16 k-chunks per kh-half: 5 VGPR + 4 LDS + 7 streamed ----
    // issue first two streamed chunks (depth-2 pipeline head)
    h8 s0 = *(const h8*)(gS);
    h8 s1 = *(const h8*)(gS + 8);
    h8 s2 = *(const h8*)(gS + 16);
    h8 s3 = *(const h8*)(gS + 24);
    h8 u0 = *(const h8*)(gS + 8192);
    h8 u1 = *(const h8*)(gS + 8192 + 8);
    h8 u2 = *(const h8*)(gS + 8192 + 16);
    h8 u3 = *(const h8*)(gS + 8192 + 24);

    float g0 = 0.f, g1 = 0.f, g2 = 0.f, g3 = 0.f;
#pragma unroll
    for (int c = 0; c < 5; ++c) {          // VGPR chunks (latency filler)
      h8 v = *(const h8*)&zf[(kh * 16 + c) * 8];
      g0 = dot8f(v, wh[c][0], g0);
      g1 = dot8f(v, wh[c][1], g1);
      g2 = dot8f(v, wh[c][2], g2);
      g3 = dot8f(v, wh[c][3], g3);
    }
#pragma unroll
    for (int c = 0; c < 4; ++c) {          // LDS chunks (q-permuted layout)
      h8 v = *(const h8*)&zf[(kh * 16 + 5 + c) * 8];
      const _Float16* lw = sW4L + (size_t)(kh * 4 + c) * 8192 + (size_t)jh4 * 8;
      g0 = dot8f(v, *(const h8*)(lw), g0);
      g1 = dot8f(v, *(const h8*)(lw + 2048), g1);
      g2 = dot8f(v, *(const h8*)(lw + 4096), g2);
      g3 = dot8f(v, *(const h8*)(lw + 6144), g3);
    }
#pragma unroll
    for (int c = 0; c < 7; ++c) {          // streamed chunks, depth-2
      h8 v = *(const h8*)&zf[(kh * 16 + 9 + c) * 8];
      g0 = dot8f(v, s0, g0);
      g1 = dot8f(v, s1, g1);
      g2 = dot8f(v, s2, g2);
      g3 = dot8f(v, s3, g3);
      s0 = u0; s1 = u1; s2 = u2; s3 = u3;
      if (c < 5) {
        const _Float16* p = gS + (size_t)(c + 2) * 8192;
        u0 = *(const h8*)(p);
        u1 = *(const h8*)(p + 8);
        u2 = *(const h8*)(p + 16);
        u3 = *(const h8*)(p + 24);
      }
    }
    { float4 o; o.x = g0; o.y = g1; o.z = g2; o.w = g3;
      *(float4*)&scrH[kh * 1024 + jh4 * 4] = o; }
    __syncthreads();                       // B3: scrH ready

    if (tid < 256) {                       // reduce 2 halves + combine
      float f1 = scrH[tid]        + scrH[1024 + tid]        + cb1;
      float f2 = scrH[256 + tid]  + scrH[1024 + 256 + tid]  + cb2;
      float ta = scrH[512 + tid]  + scrH[1024 + 512 + tid]  + cb3;
      float tb = scrH[768 + tid]  + scrH[1024 + 768 + tid]  + cb4;
      float tt = tsb[st];
      float sg = 1.f / (1.f + __expf(-(ta * tt + tb)));
      float hn = tanhf(f1) * (1.f - sg) + sg * tanhf(f2);
      xh[128 + tid] = (_Float16)hn;
      if (!INLINE_Y)
        hbuf[((size_t)b * Sn + st) * Hn + tid] = (_Float16)hn;
    }
    __syncthreads();                       // B4: h ready for next step

    if (INLINE_Y) {                        // fallback: Wo streamed per step
      const int jY = tid & 127, kq = tid >> 7;
      float y0 = 0.f, y1 = 0.f, y2 = 0.f, y3 = 0.f;
#pragma unroll
      for (int c = 0; c < 8; ++c) {
        int k8 = kq * 8 + c;
        h8 v = *(const h8*)&xh[128 + k8 * 8];
        h8 w = *(const h8*)(Wo_p + ((size_t)k8 * 128 + jY) * 8);
        dot8_4(v, w, y0, y1, y2, y3);
      }
      float ysm = y0 + y1 + y2 + y3;
      if (kq) scrY[(kq - 1) * 128 + jY] = ysm;
      __syncthreads();
      if (!kq)
        orow[(size_t)st * FOUT + jY] =
            ysm + scrY[jY] + scrY[128 + jY] + scrY[256 + jY] + boj;
    }
  }
}

// Phase 2: y[BS,128] = h[BS,256] @ Wout + bo (verified in round 4)
#define SMEMY (65536 + 4096)
extern "C" __global__ __launch_bounds__(256, 4)
void ygemm(const _Float16* __restrict__ ws, const float* __restrict__ bo,
           float* __restrict__ out) {
  extern __shared__ char ysm[];
  _Float16* sWo = (_Float16*)ysm;
  _Float16* sH  = (_Float16*)(ysm + 65536);
  const int tid = threadIdx.x;
  { const uint4* g = (const uint4*)(ws + WO_OFF);
    uint4* l = (uint4*)sWo;
#pragma unroll
    for (int i = 0; i < 16; ++i) l[tid + 256 * i] = g[tid + 256 * i]; }
  const _Float16* hb = ws + HBUF_OFF;
  const int row0 = blockIdx.x * 256;
  const int j = tid & 127, rh = tid >> 7;
  const float boj = bo[j];
  for (int it = 0; it < 32; ++it) {
    const int rbase = row0 + it * 8;
    __syncthreads();
    ((uint4*)sH)[tid] = ((const uint4*)(hb + (size_t)rbase * 256))[tid];
    __syncthreads();
#pragma unroll
    for (int rr = rh; rr < 8; rr += 2) {
      float y0 = 0.f, y1 = 0.f, y2 = 0.f, y3 = 0.f;
#pragma unroll 4
      for (int c = 0; c < 32; ++c) {
        h8 v = *(const h8*)&sH[rr * 256 + c * 8];
        h8 w = *(const h8*)&sWo[((size_t)c * 128 + j) * 8];
        dot8_4(v, w, y0, y1, y2, y3);
      }
      out[(size_t)(rbase + rr) * 128 + j] = y0 + y1 + y2 + y3 + boj;
    }
  }
}

extern "C" void kernel_launch(void* const* d_in, const int* in_sizes, int n_in,
                              void* d_out, int out_size, void* d_ws, size_t ws_size,
                              hipStream_t stream) {
  const float* x   = (const float*)d_in[0];
  const float* ts  = (const float*)d_in[1];
  const float* Wb  = (const float*)d_in[2];
  const float* bb  = (const float*)d_in[3];
  const float* W1  = (const float*)d_in[4];
  const float* bf1 = (const float*)d_in[5];
  const float* W2  = (const float*)d_in[6];
  const float* bf2 = (const float*)d_in[7];
  const float* W3  = (const float*)d_in[8];
  const float* bta = (const float*)d_in[9];
  const float* W4  = (const float*)d_in[10];
  const float* btb = (const float*)d_in[11];
  const float* Wo  = (const float*)d_in[12];
  const float* bo  = (const float*)d_in[13];
  float* out = (float*)d_out;
  _Float16* ws = (_Float16*)d_ws;

  pack_w<<<WS_HALVES / 256, 256, 0, stream>>>(Wb, W1, W2, W3, W4, Wo, ws);

  if (ws_size >= WS_SPLIT_BYTES) {
    hipFuncSetAttribute((const void*)cfc4<0>,
                        hipFuncAttributeMaxDynamicSharedMemorySize, SMEM4);
    cfc4<0><<<Bn, NT, SMEM4, stream>>>(x, ts, bb, bf1, bf2, bta, btb, bo, ws, out);
    hipFuncSetAttribute((const void*)ygemm,
                        hipFuncAttributeMaxDynamicSharedMemorySize, SMEMY);
    ygemm<<<(Bn * Sn) / 256, 256, SMEMY, stream>>>(ws, bo, out);
  } else {
    hipFuncSetAttribute((const void*)cfc4<1>,
                        hipFuncAttributeMaxDynamicSharedMemorySize, SMEM4);
    cfc4<1><<<Bn, NT, SMEM4, stream>>>(x, ts, bb, bf1, bf2, bta, btb, bo, ws, out);
  }
}